// Round 2
// baseline (202.990 us; speedup 1.0000x reference)
//
#include <hip/hip_runtime.h>

// Problem constants
// z: [8,2048,32] f32 -> N=16384 rows, D=32
// codebook: [8192,32] f32 -> K=8192 rows
// out: z_q_st (524288 f32) ++ idx (16384 f32) ++ loss (1 f32) = 540673
#define NROWS 16384
#define KCB   8192
#define DDIM  32

// ---------------- K1/K2: row L2-normalize + post-norm squared-norm ----------
// 32 lanes per row, 8 rows per 256-thread block.
__global__ __launch_bounds__(256) void norm_rows_kernel(
    const float* __restrict__ in, float* __restrict__ outv,
    float* __restrict__ outn2)
{
    int tid = threadIdx.x;
    int row = blockIdx.x * 8 + (tid >> 5);
    int l   = tid & 31;
    float x = in[row * DDIM + l];
    float s = x * x;
#pragma unroll
    for (int m = 16; m >= 1; m >>= 1) s += __shfl_xor(s, m);
    float n   = sqrtf(s);
    float den = fmaxf(n, 1e-12f);       // matches F.normalize eps semantics
    float v   = x / den;                // IEEE div (no fast-math)
    outv[row * DDIM + l] = v;
    float e = v * v;
#pragma unroll
    for (int m = 16; m >= 1; m >>= 1) e += __shfl_xor(e, m);
    if (l == 0) outn2[row] = e;         // sum(en^2) AFTER normalization (ref order)
}

// ---------------- K3: fused distance GEMM + argmin --------------------------
// Block: 256 threads = 16x16 (ty=rows, tx=cols). Tile: 128 rows x 128 cols,
// CT col-tiles per block. Per-thread 8x8 register tile.
// A staged transposed [d][row] (linear; reads are 4-address broadcast,
// conflict-free). B staged transposed with GROUP PADDING: column group
// g (8 floats) of row d lives at dword offset g*12 (48B stride, 16B-aligned)
// -> fragment bases hit 8 distinct banks (2-way max = free) instead of the
// unpadded stride-8 pattern that hits only banks {0,8,16,24} (4-way, 1.58x).
#define BM 128
#define BN 128
#define CT 4
#define BSTRIDE 192   // dwords per d-row of B: 16 groups * 12

__global__ __launch_bounds__(256) void argmin_kernel(
    const float* __restrict__ zn,  const float* __restrict__ en,
    const float* __restrict__ zn2, const float* __restrict__ en2,
    unsigned long long* __restrict__ best)
{
    __shared__ float A[DDIM][BM];        // 16 KB
    __shared__ float B[DDIM][BSTRIDE];   // 24 KB

    const int tid = threadIdx.x;
    const int tx  = tid & 15;          // col sub-tile
    const int ty  = tid >> 4;          // row sub-tile
    const int row0 = blockIdx.x * BM;
    const int cg0  = blockIdx.y * (BN * CT);

    // Stage A transposed: thread t handles row (t&127), d-quad-half (t>>7).
    {
        int r   = tid & 127;
        int dq0 = (tid >> 7) * 4;      // float4-quad base: d = (dq0+q)*4
        const float4* src = (const float4*)(zn + (size_t)(row0 + r) * DDIM) + dq0;
#pragma unroll
        for (int q = 0; q < 4; ++q) {
            float4 v = src[q];
            int d = (dq0 + q) * 4;
            A[d + 0][r] = v.x; A[d + 1][r] = v.y;
            A[d + 2][r] = v.z; A[d + 3][r] = v.w;
        }
    }

    float z2[8];
#pragma unroll
    for (int i = 0; i < 8; ++i) z2[i] = zn2[row0 + ty * 8 + i];

    float        best_s[8];
    unsigned int best_k[8];
#pragma unroll
    for (int i = 0; i < 8; ++i) {
        best_s[i] = __int_as_float(0x7F800000); // +inf
        best_k[i] = 0u;
    }

    for (int ct = 0; ct < CT; ++ct) {
        int col0 = cg0 + ct * BN;
        __syncthreads();               // previous tile's reads done (also guards A)
        {   // stage B transposed + group-padded
            int r    = tid & 127;                 // codebook row within tile
            int base = (r >> 3) * 12 + (r & 7);   // padded column slot
            int dq0  = (tid >> 7) * 4;
            const float4* src = (const float4*)(en + (size_t)(col0 + r) * DDIM) + dq0;
#pragma unroll
            for (int q = 0; q < 4; ++q) {
                float4 v = src[q];
                int d = (dq0 + q) * 4;
                B[d + 0][base] = v.x; B[d + 1][base] = v.y;
                B[d + 2][base] = v.z; B[d + 3][base] = v.w;
            }
        }
        __syncthreads();

        float acc[8][8];
#pragma unroll
        for (int i = 0; i < 8; ++i)
#pragma unroll
            for (int j = 0; j < 8; ++j) acc[i][j] = 0.f;

#pragma unroll 8
        for (int d = 0; d < DDIM; ++d) {
            float4 alo = *(const float4*)&A[d][ty * 8];
            float4 ahi = *(const float4*)&A[d][ty * 8 + 4];
            float4 blo = *(const float4*)&B[d][tx * 12];      // 16B-aligned
            float4 bhi = *(const float4*)&B[d][tx * 12 + 4];
            float a[8] = {alo.x, alo.y, alo.z, alo.w, ahi.x, ahi.y, ahi.z, ahi.w};
            float b[8] = {blo.x, blo.y, blo.z, blo.w, bhi.x, bhi.y, bhi.z, bhi.w};
#pragma unroll
            for (int i = 0; i < 8; ++i)
#pragma unroll
                for (int j = 0; j < 8; ++j)
                    acc[i][j] = fmaf(a[i], b[j], acc[i][j]);
        }

        // min-update; k ascending in j (and ct), strict < keeps first index.
        const float4* e2p = (const float4*)(en2 + col0 + tx * 8);
        float4 e2a = e2p[0], e2b = e2p[1];
        float e2[8] = {e2a.x, e2a.y, e2a.z, e2a.w, e2b.x, e2b.y, e2b.z, e2b.w};
#pragma unroll
        for (int j = 0; j < 8; ++j) {
            unsigned int k = col0 + tx * 8 + j;
#pragma unroll
            for (int i = 0; i < 8; ++i) {
                float t1 = z2[i] + e2[j];              // (|zn|^2 + |en|^2), rounded
                float s  = fmaf(-2.f, acc[i][j], t1);  // == round(t1 - 2*acc): 2*acc exact
                if (s < best_s[i]) { best_s[i] = s; best_k[i] = k; }
            }
        }
    }

    // Pack (sortable score << 32 | idx); min => smallest score, then smallest idx.
#pragma unroll
    for (int i = 0; i < 8; ++i) {
        unsigned int u = __float_as_uint(best_s[i]);
        unsigned int sortable = u ^ (unsigned int)(((int)u >> 31) | 0x80000000);
        unsigned long long p =
            ((unsigned long long)sortable << 32) | (unsigned long long)best_k[i];
#pragma unroll
        for (int m = 1; m < 16; m <<= 1) {
            unsigned long long o = __shfl_xor(p, m);
            p = (o < p) ? o : p;
        }
        if (tx == 0) atomicMin(&best[row0 + ty * 8 + i], p);
    }
}

// ---------------- K4: gather z_q, write outputs, loss partial ----------------
__global__ __launch_bounds__(256) void gather_out_kernel(
    const float* __restrict__ zn, const float* __restrict__ en,
    const unsigned long long* __restrict__ best,
    float* __restrict__ out, float* __restrict__ outidx,
    double* __restrict__ lossacc)
{
    int tid = threadIdx.x;
    int row = blockIdx.x * 8 + (tid >> 5);
    int l   = tid & 31;
    unsigned long long p = best[row];
    unsigned int idx = (unsigned int)(p & 0xFFFFFFFFull);
    float zq = en[(size_t)idx * DDIM + l];      // l2_norm(codebook[idx]) == en row
    float zv = zn[row * DDIM + l];
    float t  = zq - zv;                          // rounded
    out[row * DDIM + l] = zv + t;                // z_q_st = zn + (z_q - zn), rounded
    if (l == 0) outidx[row] = (float)idx;

    float t2 = t * t;                            // fp32 square like reference
    double s = (double)t2;
#pragma unroll
    for (int m = 32; m >= 1; m >>= 1) s += __shfl_xor(s, m);
    __shared__ double wsum[4];
    int wave = tid >> 6;
    if ((tid & 63) == 0) wsum[wave] = s;
    __syncthreads();
    if (tid == 0) {
        double tot = wsum[0] + wsum[1] + wsum[2] + wsum[3];
        atomicAdd(lossacc, tot);
    }
}

// ---------------- K5: finalize loss -----------------------------------------
__global__ void finalize_kernel(const double* __restrict__ lossacc,
                                float* __restrict__ outloss)
{
    double m = *lossacc / 524288.0;             // mean over B*T*D
    float mf = (float)m;
    *outloss = 0.25f * mf + mf;                 // BETA*m + m, same rounding as ref
}

// ---------------- launch -----------------------------------------------------
extern "C" void kernel_launch(void* const* d_in, const int* in_sizes, int n_in,
                              void* d_out, int out_size, void* d_ws, size_t ws_size,
                              hipStream_t stream)
{
    const float* z  = (const float*)d_in[0];    // 524288
    const float* cb = (const float*)d_in[1];    // 262144

    float* out     = (float*)d_out;             // z_q_st [524288]
    float* outidx  = out + 524288;              // idx as float [16384]
    float* outloss = out + 540672;              // loss [1]

    char* ws = (char*)d_ws;
    float* zn  = (float*)(ws);                   // 2 MB
    float* en  = (float*)(ws + 2097152);         // 1 MB
    float* zn2 = (float*)(ws + 3145728);         // 64 KB
    float* en2 = (float*)(ws + 3211264);         // 32 KB
    unsigned long long* best = (unsigned long long*)(ws + 3244032); // 128 KB
    double* lossacc = (double*)(ws + 3375104);   // 8 B

    hipMemsetAsync(best, 0xFF, NROWS * sizeof(unsigned long long), stream);
    hipMemsetAsync(lossacc, 0, sizeof(double), stream);

    norm_rows_kernel<<<NROWS / 8, 256, 0, stream>>>(z, zn, zn2);
    norm_rows_kernel<<<KCB / 8, 256, 0, stream>>>(cb, en, en2);

    argmin_kernel<<<dim3(NROWS / BM, KCB / (BN * CT)), 256, 0, stream>>>(
        zn, en, zn2, en2, best);

    gather_out_kernel<<<NROWS / 8, 256, 0, stream>>>(zn, en, best, out, outidx,
                                                     lossacc);
    finalize_kernel<<<1, 1, 0, stream>>>(lossacc, outloss);
}